// Round 1
// baseline (376.743 us; speedup 1.0000x reference)
//
#include <hip/hip_runtime.h>

#define NB 131072
#define NEG9 -1e9f

typedef __attribute__((ext_vector_type(8))) __bf16 bf16x8;
typedef __attribute__((ext_vector_type(4))) float f32x4;

__device__ __forceinline__ f32x4 mfma16(bf16x8 a, bf16x8 b, f32x4 c) {
    return __builtin_amdgcn_mfma_f32_16x16x32_bf16(a, b, c, 0, 0, 0);
}

// float -> bf16 (RNE), storage as ushort
__device__ __forceinline__ unsigned short f2bf(float f) {
    unsigned u = __builtin_bit_cast(unsigned, f);
    u += 0x7fffu + ((u >> 16) & 1u);
    return (unsigned short)(u >> 16);
}

// BN-folded, transposed (n-major, k-contiguous) bf16 weights + fp32 biases.
struct __align__(16) Wspace {
    unsigned short W0t[512][64];    // W0t[n][k] = W0[k][n] * s0[n]
    unsigned short W1t[256][512];   // W1t[n][k] = W1[k][n] * s1[n]
    unsigned short nW1t[64][256];
    unsigned short dW1t[64][256];
    unsigned short nW2t[128][64];
    unsigned short dW2t[128][64];
    float c0[512];
    float c1[256];
    float nb1c[64], db1c[64];
    float nb2c[128], db2c[128];
};

__device__ Wspace g_ws;  // static device workspace (rewritten every launch by prep)

__global__ void prep_kernel(
    const float* __restrict__ W0, const float* __restrict__ b0,
    const float* __restrict__ g0, const float* __restrict__ be0,
    const float* __restrict__ rm0, const float* __restrict__ rv0,
    const float* __restrict__ W1, const float* __restrict__ b1,
    const float* __restrict__ g1, const float* __restrict__ be1,
    const float* __restrict__ rm1, const float* __restrict__ rv1,
    const float* __restrict__ nW1, const float* __restrict__ nb1,
    const float* __restrict__ nW2, const float* __restrict__ nb2,
    const float* __restrict__ dW1, const float* __restrict__ db1,
    const float* __restrict__ dW2, const float* __restrict__ db2)
{
    const int tid = blockIdx.x * 256 + threadIdx.x;  // 0 .. 131071

    // W1t [256][512]: read coalesced from W1 [512][256], write scattered
    {
        int k = tid >> 8, n = tid & 255;
        float s = g1[n] * rsqrtf(rv1[n] + 1e-5f);
        g_ws.W1t[n][k] = f2bf(W1[tid] * s);
    }
    if (tid < 512 * 64) {  // W0 [64][512] -> W0t [512][64]
        int k = tid >> 9, n = tid & 511;
        float s = g0[n] * rsqrtf(rv0[n] + 1e-5f);
        g_ws.W0t[n][k] = f2bf(W0[tid] * s);
        (void)k;
    }
    if (tid < 256 * 64) {  // nW1/dW1 [256][64] -> [64][256]
        int k = tid >> 6, n = tid & 63;
        g_ws.nW1t[n][k] = f2bf(nW1[tid]);
        g_ws.dW1t[n][k] = f2bf(dW1[tid]);
    }
    if (tid < 64 * 128) {  // nW2/dW2 [64][128] -> [128][64]
        int k = tid >> 7, n = tid & 127;
        g_ws.nW2t[n][k] = f2bf(nW2[tid]);
        g_ws.dW2t[n][k] = f2bf(dW2[tid]);
    }
    if (tid < 512) g_ws.c0[tid] = (b0[tid] - rm0[tid]) * (g0[tid] * rsqrtf(rv0[tid] + 1e-5f)) + be0[tid];
    if (tid < 256) g_ws.c1[tid] = (b1[tid] - rm1[tid]) * (g1[tid] * rsqrtf(rv1[tid] + 1e-5f)) + be1[tid];
    if (tid < 64) { g_ws.nb1c[tid] = nb1[tid]; g_ws.db1c[tid] = db1[tid]; }
    if (tid < 128) { g_ws.nb2c[tid] = nb2[tid]; g_ws.db2c[tid] = db2[tid]; }
}

// One block = 4 waves, 32 rows. Waves split the N dimension of each layer.
__global__ __launch_bounds__(256, 2) void fused_mlp(
    const float* __restrict__ x, float* __restrict__ out)
{
    // bf16 LDS tiles, rows padded +8 elems (stride = 4 banks -> 2-way = free)
    __shared__ __align__(16) unsigned short Xs[32][72];
    __shared__ __align__(16) unsigned short H0[32][520];
    __shared__ __align__(16) unsigned short H1[32][264];
    __shared__ __align__(16) unsigned short An[32][72];
    __shared__ __align__(16) unsigned short Ad[32][72];
    __shared__ int scl[2][32];

    const int tid = threadIdx.x;
    const int w = tid >> 6;        // wave 0..3
    const int lane = tid & 63;
    const int m = lane & 15;       // A-row / B-col / C-col index
    const int q = lane >> 4;       // quad 0..3
    const int row0 = blockIdx.x * 32;

    // ---- stage X (fp32 -> bf16) + class thresholds ----
    for (int i = tid; i < 32 * 64; i += 256) {
        int r = i >> 6, c = i & 63;
        Xs[r][c] = f2bf(x[(size_t)(row0 + r) * 64 + c]);
    }
    if (tid < 32) scl[0][tid] = (int)x[(size_t)(row0 + tid) * 64 + 60];
    else if (tid < 64) scl[1][tid - 32] = (int)x[(size_t)(row0 + tid - 32) * 64 + 61];
    __syncthreads();

    // ---- layer 0: H0 = relu(X @ W0' + c0). Wave w owns cols [w*128, w*128+128) ----
    for (int nt = 0; nt < 8; ++nt) {
        const int col = w * 128 + nt * 16 + m;
        bf16x8 b0 = *(const bf16x8*)&g_ws.W0t[col][q * 8];
        bf16x8 b1 = *(const bf16x8*)&g_ws.W0t[col][32 + q * 8];
        float bias = g_ws.c0[col];
        for (int mt = 0; mt < 2; ++mt) {
            bf16x8 a0 = *(const bf16x8*)&Xs[mt * 16 + m][q * 8];
            bf16x8 a1 = *(const bf16x8*)&Xs[mt * 16 + m][32 + q * 8];
            f32x4 c = {0.f, 0.f, 0.f, 0.f};
            c = mfma16(a0, b0, c);
            c = mfma16(a1, b1, c);
#pragma unroll
            for (int r = 0; r < 4; ++r) {
                float v = c[r] + bias;
                H0[mt * 16 + q * 4 + r][col] = f2bf(fmaxf(v, 0.f));
            }
        }
    }
    __syncthreads();

    // ---- layer 1: H1 = relu(H0 @ W1' + c1). Wave w owns cols [w*64, w*64+64) ----
    for (int nt = 0; nt < 4; ++nt) {
        const int col = w * 64 + nt * 16 + m;
        f32x4 cA = {0.f, 0.f, 0.f, 0.f}, cB = {0.f, 0.f, 0.f, 0.f};
        for (int k0 = 0; k0 < 512; k0 += 32) {
            bf16x8 b = *(const bf16x8*)&g_ws.W1t[col][k0 + q * 8];
            bf16x8 a0 = *(const bf16x8*)&H0[m][k0 + q * 8];
            bf16x8 a1 = *(const bf16x8*)&H0[16 + m][k0 + q * 8];
            cA = mfma16(a0, b, cA);
            cB = mfma16(a1, b, cB);
        }
        float bias = g_ws.c1[col];
#pragma unroll
        for (int r = 0; r < 4; ++r) {
            H1[q * 4 + r][col] = f2bf(fmaxf(cA[r] + bias, 0.f));
            H1[16 + q * 4 + r][col] = f2bf(fmaxf(cB[r] + bias, 0.f));
        }
    }
    __syncthreads();

    // ---- head layer 1: A = relu(H1 @ {n,d}W1 + b). waves 0,1 -> nurse; 2,3 -> doctor.
    {
        const unsigned short (*Wh)[256] = (w < 2) ? g_ws.nW1t : g_ws.dW1t;
        const float* bh = (w < 2) ? g_ws.nb1c : g_ws.db1c;
        unsigned short (*Ah)[72] = (w < 2) ? An : Ad;
        const int nbase = (w & 1) * 32;
        for (int nt = 0; nt < 2; ++nt) {
            const int col = nbase + nt * 16 + m;
            f32x4 cA = {0.f, 0.f, 0.f, 0.f}, cB = {0.f, 0.f, 0.f, 0.f};
            for (int k0 = 0; k0 < 256; k0 += 32) {
                bf16x8 b = *(const bf16x8*)&Wh[col][k0 + q * 8];
                bf16x8 a0 = *(const bf16x8*)&H1[m][k0 + q * 8];
                bf16x8 a1 = *(const bf16x8*)&H1[16 + m][k0 + q * 8];
                cA = mfma16(a0, b, cA);
                cB = mfma16(a1, b, cB);
            }
            float bias = bh[col];
#pragma unroll
            for (int r = 0; r < 4; ++r) {
                Ah[q * 4 + r][col] = f2bf(fmaxf(cA[r] + bias, 0.f));
                Ah[16 + q * 4 + r][col] = f2bf(fmaxf(cB[r] + bias, 0.f));
            }
        }
    }
    __syncthreads();

    // ---- head layer 2 + mask + store. waves 0,1 -> nurse cols 0-63/64-127; 2,3 -> doctor.
    {
        const int head = w >> 1;
        const unsigned short (*W2)[64] = head ? g_ws.dW2t : g_ws.nW2t;
        const float* b2 = head ? g_ws.db2c : g_ws.nb2c;
        const unsigned short (*Ah)[72] = head ? Ad : An;
        const int* sc = scl[head];
        float* op = out + (size_t)head * NB * 128;
        for (int t = 0; t < 4; ++t) {
            const int col = ((w & 1) * 4 + t) * 16 + m;
            bf16x8 bA = *(const bf16x8*)&W2[col][q * 8];
            bf16x8 bB = *(const bf16x8*)&W2[col][32 + q * 8];
            float bias = b2[col];
            for (int mt = 0; mt < 2; ++mt) {
                bf16x8 a0 = *(const bf16x8*)&Ah[mt * 16 + m][q * 8];
                bf16x8 a1 = *(const bf16x8*)&Ah[mt * 16 + m][32 + q * 8];
                f32x4 c = {0.f, 0.f, 0.f, 0.f};
                c = mfma16(a0, bA, c);
                c = mfma16(a1, bB, c);
#pragma unroll
                for (int r = 0; r < 4; ++r) {
                    int row = mt * 16 + q * 4 + r;
                    float v = c[r] + bias;
                    v = (col <= sc[row]) ? v : NEG9;
                    op[(size_t)(row0 + row) * 128 + col] = v;
                }
            }
        }
    }
}

extern "C" void kernel_launch(void* const* d_in, const int* in_sizes, int n_in,
                              void* d_out, int out_size, void* d_ws, size_t ws_size,
                              hipStream_t stream) {
    (void)in_sizes; (void)n_in; (void)d_ws; (void)ws_size;
    const float* x = (const float*)d_in[0];

    prep_kernel<<<512, 256, 0, stream>>>(
        (const float*)d_in[1], (const float*)d_in[2], (const float*)d_in[3],
        (const float*)d_in[4], (const float*)d_in[5], (const float*)d_in[6],
        (const float*)d_in[7], (const float*)d_in[8], (const float*)d_in[9],
        (const float*)d_in[10], (const float*)d_in[11], (const float*)d_in[12],
        (const float*)d_in[13], (const float*)d_in[14], (const float*)d_in[15],
        (const float*)d_in[16], (const float*)d_in[17], (const float*)d_in[18],
        (const float*)d_in[19], (const float*)d_in[20]);

    fused_mlp<<<NB / 32, 256, 0, stream>>>(x, (float*)d_out);
}

// Round 2
// 292.324 us; speedup vs baseline: 1.2888x; 1.2888x over previous
//
#include <hip/hip_runtime.h>

#define NB 131072
#define NEG9 -1e9f

typedef __attribute__((ext_vector_type(8))) __bf16 bf16x8;
typedef __attribute__((ext_vector_type(4))) float f32x4;
typedef __attribute__((ext_vector_type(4))) unsigned short u16x4;

__device__ __forceinline__ f32x4 mfma16(bf16x8 a, bf16x8 b, f32x4 c) {
    return __builtin_amdgcn_mfma_f32_16x16x32_bf16(a, b, c, 0, 0, 0);
}

// float -> bf16 (RNE), storage as ushort
__device__ __forceinline__ unsigned short f2bf(float f) {
    unsigned u = __builtin_bit_cast(unsigned, f);
    u += 0x7fffu + ((u >> 16) & 1u);
    return (unsigned short)(u >> 16);
}

// BN-folded, transposed (n-major, k-contiguous) bf16 weights + fp32 biases.
struct __align__(16) Wspace {
    unsigned short W0t[512][64];    // W0t[n][k] = W0[k][n] * s0[n]
    unsigned short W1t[256][512];   // W1t[n][k] = W1[k][n] * s1[n]
    unsigned short nW1t[64][256];
    unsigned short dW1t[64][256];
    unsigned short nW2t[128][64];
    unsigned short dW2t[128][64];
    float c0[512];
    float c1[256];
    float nb1c[64], db1c[64];
    float nb2c[128], db2c[128];
};

__device__ Wspace g_ws;

// All transposes: coalesced WRITES (consecutive tid -> consecutive u16),
// strided reads (L2-served; source weights total < 1 MB).
__global__ void prep_kernel(
    const float* __restrict__ W0, const float* __restrict__ b0,
    const float* __restrict__ g0, const float* __restrict__ be0,
    const float* __restrict__ rm0, const float* __restrict__ rv0,
    const float* __restrict__ W1, const float* __restrict__ b1,
    const float* __restrict__ g1, const float* __restrict__ be1,
    const float* __restrict__ rm1, const float* __restrict__ rv1,
    const float* __restrict__ nW1, const float* __restrict__ nb1,
    const float* __restrict__ nW2, const float* __restrict__ nb2,
    const float* __restrict__ dW1, const float* __restrict__ db1,
    const float* __restrict__ dW2, const float* __restrict__ db2)
{
    const int tid = blockIdx.x * 256 + threadIdx.x;  // 0 .. 131071

    {   // W1t [256][512], flat idx = tid: n = tid>>9, k = tid&511
        int n = tid >> 9, k = tid & 511;
        float s = g1[n] * rsqrtf(rv1[n] + 1e-5f);
        ((unsigned short*)g_ws.W1t)[tid] = f2bf(W1[k * 256 + n] * s);
    }
    if (tid < 512 * 64) {  // W0t [512][64]: n = tid>>6, k = tid&63
        int n = tid >> 6, k = tid & 63;
        float s = g0[n] * rsqrtf(rv0[n] + 1e-5f);
        ((unsigned short*)g_ws.W0t)[tid] = f2bf(W0[k * 512 + n] * s);
    }
    if (tid < 64 * 256) {  // nW1t/dW1t [64][256]: n = tid>>8, k = tid&255
        int n = tid >> 8, k = tid & 255;
        ((unsigned short*)g_ws.nW1t)[tid] = f2bf(nW1[k * 64 + n]);
        ((unsigned short*)g_ws.dW1t)[tid] = f2bf(dW1[k * 64 + n]);
    }
    if (tid < 128 * 64) {  // nW2t/dW2t [128][64]: n = tid>>6, k = tid&63
        int n = tid >> 6, k = tid & 63;
        ((unsigned short*)g_ws.nW2t)[tid] = f2bf(nW2[k * 128 + n]);
        ((unsigned short*)g_ws.dW2t)[tid] = f2bf(dW2[k * 128 + n]);
    }
    if (tid < 512) g_ws.c0[tid] = (b0[tid] - rm0[tid]) * (g0[tid] * rsqrtf(rv0[tid] + 1e-5f)) + be0[tid];
    if (tid < 256) g_ws.c1[tid] = (b1[tid] - rm1[tid]) * (g1[tid] * rsqrtf(rv1[tid] + 1e-5f)) + be1[tid];
    if (tid < 64) { g_ws.nb1c[tid] = nb1[tid]; g_ws.db1c[tid] = db1[tid]; }
    if (tid < 128) { g_ws.nb2c[tid] = nb2[tid]; g_ws.db2c[tid] = db2[tid]; }
}

// 1 block = 4 waves = 64 rows. Layer0/1 chunked over K (2 x 256) with
// layer-1 partials in registers (16 independent accumulator tiles / wave).
// LDS overlays: An->Xs, H1->H0c. Total ~52.7 KB -> 3 blocks/CU.
__global__ __launch_bounds__(256, 3) void fused_mlp(
    const float4* __restrict__ x4, float* __restrict__ out)
{
    __shared__ __align__(16) unsigned short sXs[64 * 72];   // X (bf16); later An
    __shared__ __align__(16) unsigned short sH0[64 * 264];  // H0 chunk; later H1
    __shared__ __align__(16) unsigned short sAd[64 * 72];   // doctor head act
    __shared__ int scl[2][64];

    const int tid = threadIdx.x;
    const int w = tid >> 6;
    const int lane = tid & 63;
    const int m = lane & 15;
    const int q = lane >> 4;
    const int row0 = blockIdx.x * 64;

    // ---- stage X (fp32 -> bf16, float4 loads) + class thresholds ----
    for (int i = tid; i < 64 * 16; i += 256) {
        int r = i >> 4, c4 = i & 15;
        float4 v = x4[(size_t)(row0 + r) * 16 + c4];
        u16x4 p = { f2bf(v.x), f2bf(v.y), f2bf(v.z), f2bf(v.w) };
        *(u16x4*)&sXs[r * 72 + c4 * 4] = p;
        if (c4 == 15) { scl[0][r] = (int)v.x; scl[1][r] = (int)v.y; }  // cols 60,61
    }
    __syncthreads();

    // ---- layers 0+1, K-chunked; layer-1 partials live in regs ----
    f32x4 acc1[4][4];  // [nt][mt], wave w owns H1 cols [w*64, w*64+64)
#pragma unroll
    for (int a = 0; a < 4; ++a)
#pragma unroll
        for (int b = 0; b < 4; ++b) acc1[a][b] = f32x4{0.f, 0.f, 0.f, 0.f};

    for (int ch = 0; ch < 2; ++ch) {
        // layer0: wave w computes H0 cols [ch*256 + w*64, +64) for 64 rows
#pragma unroll
        for (int nt = 0; nt < 4; ++nt) {
            const int col = ch * 256 + w * 64 + nt * 16 + m;
            const int lc = w * 64 + nt * 16 + m;  // col within chunk
            bf16x8 b0 = *(const bf16x8*)&g_ws.W0t[col][q * 8];
            bf16x8 b1 = *(const bf16x8*)&g_ws.W0t[col][32 + q * 8];
            float bias = g_ws.c0[col];
#pragma unroll
            for (int mt = 0; mt < 4; ++mt) {
                bf16x8 a0 = *(const bf16x8*)&sXs[(mt * 16 + m) * 72 + q * 8];
                bf16x8 a1 = *(const bf16x8*)&sXs[(mt * 16 + m) * 72 + 32 + q * 8];
                f32x4 c = {0.f, 0.f, 0.f, 0.f};
                c = mfma16(a0, b0, c);
                c = mfma16(a1, b1, c);
#pragma unroll
                for (int r = 0; r < 4; ++r)
                    sH0[(mt * 16 + q * 4 + r) * 264 + lc] = f2bf(fmaxf(c[r] + bias, 0.f));
            }
        }
        __syncthreads();

        // layer1 partial over this K-chunk: 16 indep accum tiles, unrolled
#pragma unroll
        for (int ks = 0; ks < 8; ++ks) {
            const int k0 = ks * 32;
            bf16x8 bfr[4], afr[4];
#pragma unroll
            for (int nt = 0; nt < 4; ++nt)
                bfr[nt] = *(const bf16x8*)&g_ws.W1t[w * 64 + nt * 16 + m][ch * 256 + k0 + q * 8];
#pragma unroll
            for (int mt = 0; mt < 4; ++mt)
                afr[mt] = *(const bf16x8*)&sH0[(mt * 16 + m) * 264 + k0 + q * 8];
#pragma unroll
            for (int nt = 0; nt < 4; ++nt)
#pragma unroll
                for (int mt = 0; mt < 4; ++mt)
                    acc1[nt][mt] = mfma16(afr[mt], bfr[nt], acc1[nt][mt]);
        }
        __syncthreads();  // before chunk2 overwrites sH0 (or before H1 write)
    }

    // ---- H1 = relu(acc1 + c1) -> sH0 (reused as H1 [64][264]) ----
#pragma unroll
    for (int nt = 0; nt < 4; ++nt) {
        const int col = w * 64 + nt * 16 + m;
        float bias = g_ws.c1[col];
#pragma unroll
        for (int mt = 0; mt < 4; ++mt)
#pragma unroll
            for (int r = 0; r < 4; ++r)
                sH0[(mt * 16 + q * 4 + r) * 264 + col] = f2bf(fmaxf(acc1[nt][mt][r] + bias, 0.f));
    }
    __syncthreads();

    // ---- head layer 1: waves 0,1 -> nurse (cols (w&1)*32..+32); 2,3 -> doctor ----
    {
        const int head = w >> 1;
        const unsigned short (*Wh)[256] = head ? g_ws.dW1t : g_ws.nW1t;
        const float* bh = head ? g_ws.db1c : g_ws.nb1c;
        unsigned short* Ah = head ? sAd : sXs;  // An overlays Xs (X dead now)
        f32x4 acc[2][4];
#pragma unroll
        for (int a = 0; a < 2; ++a)
#pragma unroll
            for (int b = 0; b < 4; ++b) acc[a][b] = f32x4{0.f, 0.f, 0.f, 0.f};
#pragma unroll
        for (int ks = 0; ks < 8; ++ks) {
            const int k0 = ks * 32;
            bf16x8 bfr[2], afr[4];
#pragma unroll
            for (int nt = 0; nt < 2; ++nt)
                bfr[nt] = *(const bf16x8*)&Wh[(w & 1) * 32 + nt * 16 + m][k0 + q * 8];
#pragma unroll
            for (int mt = 0; mt < 4; ++mt)
                afr[mt] = *(const bf16x8*)&sH0[(mt * 16 + m) * 264 + k0 + q * 8];
#pragma unroll
            for (int nt = 0; nt < 2; ++nt)
#pragma unroll
                for (int mt = 0; mt < 4; ++mt)
                    acc[nt][mt] = mfma16(afr[mt], bfr[nt], acc[nt][mt]);
        }
#pragma unroll
        for (int nt = 0; nt < 2; ++nt) {
            const int col = (w & 1) * 32 + nt * 16 + m;
            float bias = bh[col];
#pragma unroll
            for (int mt = 0; mt < 4; ++mt)
#pragma unroll
                for (int r = 0; r < 4; ++r)
                    Ah[(mt * 16 + q * 4 + r) * 72 + col] = f2bf(fmaxf(acc[nt][mt][r] + bias, 0.f));
        }
    }
    __syncthreads();

    // ---- head layer 2 + mask + store ----
    {
        const int head = w >> 1;
        const unsigned short (*W2)[64] = head ? g_ws.dW2t : g_ws.nW2t;
        const float* b2 = head ? g_ws.db2c : g_ws.nb2c;
        const unsigned short* Ah = head ? sAd : sXs;
        const int* sc = scl[head];
        float* op = out + (size_t)head * (size_t)NB * 128;

        bf16x8 a0f[4], a1f[4];
#pragma unroll
        for (int mt = 0; mt < 4; ++mt) {
            a0f[mt] = *(const bf16x8*)&Ah[(mt * 16 + m) * 72 + q * 8];
            a1f[mt] = *(const bf16x8*)&Ah[(mt * 16 + m) * 72 + 32 + q * 8];
        }
#pragma unroll
        for (int ct = 0; ct < 4; ++ct) {
            const int col = (w & 1) * 64 + ct * 16 + m;
            bf16x8 b0 = *(const bf16x8*)&W2[col][q * 8];
            bf16x8 b1 = *(const bf16x8*)&W2[col][32 + q * 8];
            float bias = b2[col];
#pragma unroll
            for (int mt = 0; mt < 4; ++mt) {
                f32x4 c = {0.f, 0.f, 0.f, 0.f};
                c = mfma16(a0f[mt], b0, c);
                c = mfma16(a1f[mt], b1, c);
#pragma unroll
                for (int r = 0; r < 4; ++r) {
                    const int row = mt * 16 + q * 4 + r;
                    float v = c[r] + bias;
                    v = (col <= sc[row]) ? v : NEG9;
                    op[(size_t)(row0 + row) * 128 + col] = v;
                }
            }
        }
    }
}

extern "C" void kernel_launch(void* const* d_in, const int* in_sizes, int n_in,
                              void* d_out, int out_size, void* d_ws, size_t ws_size,
                              hipStream_t stream) {
    (void)in_sizes; (void)n_in; (void)d_ws; (void)ws_size;

    prep_kernel<<<512, 256, 0, stream>>>(
        (const float*)d_in[1], (const float*)d_in[2], (const float*)d_in[3],
        (const float*)d_in[4], (const float*)d_in[5], (const float*)d_in[6],
        (const float*)d_in[7], (const float*)d_in[8], (const float*)d_in[9],
        (const float*)d_in[10], (const float*)d_in[11], (const float*)d_in[12],
        (const float*)d_in[13], (const float*)d_in[14], (const float*)d_in[15],
        (const float*)d_in[16], (const float*)d_in[17], (const float*)d_in[18],
        (const float*)d_in[19], (const float*)d_in[20]);

    fused_mlp<<<NB / 64, 256, 0, stream>>>((const float4*)d_in[0], (float*)d_out);
}